// Round 1
// baseline (2129.223 us; speedup 1.0000x reference)
//
#include <hip/hip_runtime.h>

#define D 96
#define D4 24   // D/4 float4 groups per row

// ---------------------------------------------------------------------------
// Scatter-add: aggr[dst[e]] += x[src[e]] over all edges, 96 feats per edge.
// One thread handles one (edge, float4-group): 4 atomicAdds.
// ---------------------------------------------------------------------------
__global__ void scatter_add_kernel(const float* __restrict__ x,
                                   const int* __restrict__ src,
                                   const int* __restrict__ dst,
                                   float* __restrict__ aggr,
                                   int E) {
    const int total = E * D4;            // 19.2M < 2^31
    for (int i = blockIdx.x * blockDim.x + threadIdx.x; i < total;
         i += gridDim.x * blockDim.x) {
        const int e = i / D4;
        const int q = i - e * D4;
        const int s = src[e];
        const int d = dst[e];
        const float4 v = ((const float4*)(x + (size_t)s * D))[q];
        float* a = aggr + (size_t)d * D + q * 4;
        atomicAdd(a + 0, v.x);
        atomicAdd(a + 1, v.y);
        atomicAdd(a + 2, v.z);
        atomicAdd(a + 3, v.w);
    }
}

// ---------------------------------------------------------------------------
// h = relu((x + aggr) @ W1 + b1).  Thread per node. W1 (96x96) staged in LDS,
// read as broadcast float4; input row and 96 accumulators in registers.
// ---------------------------------------------------------------------------
__global__ void lin1_relu_kernel(const float* __restrict__ x,
                                 const float* __restrict__ aggr,
                                 const float* __restrict__ W,   // [96][96] row-major [k][o]
                                 const float* __restrict__ b,   // [96]
                                 float* __restrict__ h,
                                 int n) {
    __shared__ float4 Ws[D * D4];        // 96*24 float4 = 36.9 KB
    for (int i = threadIdx.x; i < D * D4; i += blockDim.x)
        Ws[i] = ((const float4*)W)[i];
    __syncthreads();

    const int node = blockIdx.x * blockDim.x + threadIdx.x;
    if (node >= n) return;

    float xin[D];
    const float4* xr = (const float4*)(x + (size_t)node * D);
    const float4* ar = (const float4*)(aggr + (size_t)node * D);
#pragma unroll
    for (int q = 0; q < D4; ++q) {
        const float4 a = xr[q];
        const float4 c = ar[q];
        xin[q * 4 + 0] = a.x + c.x;
        xin[q * 4 + 1] = a.y + c.y;
        xin[q * 4 + 2] = a.z + c.z;
        xin[q * 4 + 3] = a.w + c.w;
    }

    float4 acc[D4];
#pragma unroll
    for (int o = 0; o < D4; ++o) acc[o] = ((const float4*)b)[o];

#pragma unroll 4
    for (int k = 0; k < D; ++k) {
        const float xv = xin[k];
#pragma unroll
        for (int o = 0; o < D4; ++o) {
            const float4 w = Ws[k * D4 + o];
            acc[o].x += xv * w.x;
            acc[o].y += xv * w.y;
            acc[o].z += xv * w.z;
            acc[o].w += xv * w.w;
        }
    }

    float4* hr = (float4*)(h + (size_t)node * D);
#pragma unroll
    for (int o = 0; o < D4; ++o) {
        float4 v = acc[o];
        v.x = fmaxf(v.x, 0.0f);
        v.y = fmaxf(v.y, 0.0f);
        v.z = fmaxf(v.z, 0.0f);
        v.w = fmaxf(v.w, 0.0f);
        hr[o] = v;
    }
}

// ---------------------------------------------------------------------------
// out = (h + aggr) @ W2 + b2.  W2 is 96x2 [k][o]; uniform reads -> scalar loads.
// ---------------------------------------------------------------------------
__global__ void lin2_kernel(const float* __restrict__ h,
                            const float* __restrict__ aggr,
                            const float* __restrict__ W,   // [96][2]
                            const float* __restrict__ b,   // [2]
                            float* __restrict__ out,
                            int n) {
    const int node = blockIdx.x * blockDim.x + threadIdx.x;
    if (node >= n) return;

    float acc0 = b[0];
    float acc1 = b[1];
    const float4* hr = (const float4*)(h + (size_t)node * D);
    const float4* ar = (const float4*)(aggr + (size_t)node * D);
#pragma unroll
    for (int q = 0; q < D4; ++q) {
        const float4 a = hr[q];
        const float4 c = ar[q];
        const float v0 = a.x + c.x;
        const float v1 = a.y + c.y;
        const float v2 = a.z + c.z;
        const float v3 = a.w + c.w;
        const int k = q * 4;
        acc0 += v0 * W[2 * k + 0] + v1 * W[2 * k + 2] + v2 * W[2 * k + 4] + v3 * W[2 * k + 6];
        acc1 += v0 * W[2 * k + 1] + v1 * W[2 * k + 3] + v2 * W[2 * k + 5] + v3 * W[2 * k + 7];
    }
    float2 r;
    r.x = acc0;
    r.y = acc1;
    ((float2*)out)[node] = r;
}

// ---------------------------------------------------------------------------
extern "C" void kernel_launch(void* const* d_in, const int* in_sizes, int n_in,
                              void* d_out, int out_size, void* d_ws, size_t ws_size,
                              hipStream_t stream) {
    const float* x   = (const float*)d_in[0];
    const int*   eix = (const int*)d_in[1];    // [2][E], int32 per harness contract
    const float* W1  = (const float*)d_in[2];
    const float* b1  = (const float*)d_in[3];
    const float* W2  = (const float*)d_in[4];
    const float* b2  = (const float*)d_in[5];
    float*       out = (float*)d_out;

    const int n = in_sizes[0] / D;       // 50000
    const int E = in_sizes[1] / 2;       // 800000

    // ws layout: aggr [n*D] | h [n*D]   (38.4 MB total)
    float* aggr = (float*)d_ws;
    float* h    = aggr + (size_t)n * D;

    const int* src = eix;
    const int* dst = eix + E;

    const size_t aggr_bytes = (size_t)n * D * sizeof(float);
    const int lin_blocks = (n + 255) / 256;

    // Layer 1
    hipMemsetAsync(aggr, 0, aggr_bytes, stream);
    scatter_add_kernel<<<4096, 256, 0, stream>>>(x, src, dst, aggr, E);
    lin1_relu_kernel<<<lin_blocks, 256, 0, stream>>>(x, aggr, W1, b1, h, n);

    // Layer 2 (reuse aggr buffer)
    hipMemsetAsync(aggr, 0, aggr_bytes, stream);
    scatter_add_kernel<<<4096, 256, 0, stream>>>(h, src, dst, aggr, E);
    lin2_kernel<<<lin_blocks, 256, 0, stream>>>(h, aggr, W2, b2, out, n);
}

// Round 2
// 322.411 us; speedup vs baseline: 6.6041x; 6.6041x over previous
//
#include <hip/hip_runtime.h>

#define D 96
#define D4 24   // D/4 float4 groups per row

// ===========================================================================
// CSR build: histogram of dst -> exclusive scan -> slot-fill of src ids.
// ===========================================================================
__global__ void hist_kernel(const int* __restrict__ dst, int* __restrict__ cnt, int E) {
    const int i = blockIdx.x * blockDim.x + threadIdx.x;
    if (i < E) atomicAdd(&cnt[dst[i]], 1);
}

// Per-block inclusive scan (1024 threads) -> exclusive local offsets + block totals.
__global__ void blockscan_kernel(const int* __restrict__ cnt, int* __restrict__ off,
                                 int* __restrict__ btot, int n) {
    __shared__ int tmp[1024];
    const int tid = threadIdx.x;
    const int gid = blockIdx.x * 1024 + tid;
    const int v = (gid < n) ? cnt[gid] : 0;
    tmp[tid] = v;
    __syncthreads();
    for (int ofs = 1; ofs < 1024; ofs <<= 1) {
        int t = 0;
        if (tid >= ofs) t = tmp[tid - ofs];
        __syncthreads();
        if (tid >= ofs) tmp[tid] += t;
        __syncthreads();
    }
    if (gid < n) off[gid] = tmp[tid] - v;          // exclusive within block
    if (tid == 1023) btot[blockIdx.x] = tmp[1023]; // block total
}

// Serial scan of block totals (nb ~ 49; trivial).
__global__ void scantot_kernel(int* __restrict__ btot, int nb) {
    if (blockIdx.x == 0 && threadIdx.x == 0) {
        int run = 0;
        for (int i = 0; i < nb; ++i) { const int v = btot[i]; btot[i] = run; run += v; }
    }
}

__global__ void addoff_kernel(int* __restrict__ off, int* __restrict__ cursor,
                              const int* __restrict__ btot, int n) {
    const int i = blockIdx.x * blockDim.x + threadIdx.x;
    if (i < n) {
        const int o = off[i] + btot[i >> 10];
        off[i] = o;
        cursor[i] = o;
    }
}

__global__ void fill_kernel(const int* __restrict__ src, const int* __restrict__ dst,
                            int* __restrict__ cursor, int* __restrict__ srcs, int E) {
    const int i = blockIdx.x * blockDim.x + threadIdx.x;
    if (i < E) {
        const int p = atomicAdd(&cursor[dst[i]], 1);
        srcs[p] = src[i];
    }
}

// ===========================================================================
// Gather-reduce: aggr[node] = sum over in-edges of feat[src]. Thread =
// (node, float4-group); 24 consecutive threads share a node (coalesced rows).
// ===========================================================================
__global__ void gather_kernel(const float* __restrict__ feat,
                              const int* __restrict__ off,
                              const int* __restrict__ cnt,
                              const int* __restrict__ srcs,
                              float* __restrict__ aggr, int n) {
    const int i = blockIdx.x * blockDim.x + threadIdx.x;
    if (i >= n * D4) return;
    const int node = i / D4;
    const int q = i - node * D4;
    const int s0 = off[node];
    const int deg = cnt[node];
    const int* sl = srcs + s0;
    float4 acc = make_float4(0.f, 0.f, 0.f, 0.f);
    for (int p = 0; p < deg; ++p) {
        const int s = sl[p];
        const float4 v = ((const float4*)(feat + (size_t)s * D))[q];
        acc.x += v.x; acc.y += v.y; acc.z += v.z; acc.w += v.w;
    }
    ((float4*)(aggr + (size_t)node * D))[q] = acc;
}

// ===========================================================================
// Fallback scatter-add (atomic), used only if ws is too small for CSR.
// ===========================================================================
__global__ void scatter_add_kernel(const float* __restrict__ x,
                                   const int* __restrict__ src,
                                   const int* __restrict__ dst,
                                   float* __restrict__ aggr, int E) {
    const int total = E * D4;
    for (int i = blockIdx.x * blockDim.x + threadIdx.x; i < total;
         i += gridDim.x * blockDim.x) {
        const int e = i / D4;
        const int q = i - e * D4;
        const float4 v = ((const float4*)(x + (size_t)src[e] * D))[q];
        float* a = aggr + (size_t)dst[e] * D + q * 4;
        atomicAdd(a + 0, v.x);
        atomicAdd(a + 1, v.y);
        atomicAdd(a + 2, v.z);
        atomicAdd(a + 3, v.w);
    }
}

// ===========================================================================
// h = relu((x + aggr) @ W1 + b1). Thread per node, W1 in LDS.
// ===========================================================================
__global__ void lin1_relu_kernel(const float* __restrict__ x,
                                 const float* __restrict__ aggr,
                                 const float* __restrict__ W,
                                 const float* __restrict__ b,
                                 float* __restrict__ h, int n) {
    __shared__ float4 Ws[D * D4];
    for (int i = threadIdx.x; i < D * D4; i += blockDim.x)
        Ws[i] = ((const float4*)W)[i];
    __syncthreads();

    const int node = blockIdx.x * blockDim.x + threadIdx.x;
    if (node >= n) return;

    float xin[D];
    const float4* xr = (const float4*)(x + (size_t)node * D);
    const float4* ar = (const float4*)(aggr + (size_t)node * D);
#pragma unroll
    for (int q = 0; q < D4; ++q) {
        const float4 a = xr[q];
        const float4 c = ar[q];
        xin[q * 4 + 0] = a.x + c.x;
        xin[q * 4 + 1] = a.y + c.y;
        xin[q * 4 + 2] = a.z + c.z;
        xin[q * 4 + 3] = a.w + c.w;
    }

    float4 acc[D4];
#pragma unroll
    for (int o = 0; o < D4; ++o) acc[o] = ((const float4*)b)[o];

#pragma unroll 4
    for (int k = 0; k < D; ++k) {
        const float xv = xin[k];
#pragma unroll
        for (int o = 0; o < D4; ++o) {
            const float4 w = Ws[k * D4 + o];
            acc[o].x += xv * w.x;
            acc[o].y += xv * w.y;
            acc[o].z += xv * w.z;
            acc[o].w += xv * w.w;
        }
    }

    float4* hr = (float4*)(h + (size_t)node * D);
#pragma unroll
    for (int o = 0; o < D4; ++o) {
        float4 v = acc[o];
        v.x = fmaxf(v.x, 0.0f);
        v.y = fmaxf(v.y, 0.0f);
        v.z = fmaxf(v.z, 0.0f);
        v.w = fmaxf(v.w, 0.0f);
        hr[o] = v;
    }
}

// ===========================================================================
// out = (h + aggr) @ W2 + b2.  W2 is [96][2].
// ===========================================================================
__global__ void lin2_kernel(const float* __restrict__ h,
                            const float* __restrict__ aggr,
                            const float* __restrict__ W,
                            const float* __restrict__ b,
                            float* __restrict__ out, int n) {
    const int node = blockIdx.x * blockDim.x + threadIdx.x;
    if (node >= n) return;

    float acc0 = b[0];
    float acc1 = b[1];
    const float4* hr = (const float4*)(h + (size_t)node * D);
    const float4* ar = (const float4*)(aggr + (size_t)node * D);
#pragma unroll
    for (int q = 0; q < D4; ++q) {
        const float4 a = hr[q];
        const float4 c = ar[q];
        const float v0 = a.x + c.x;
        const float v1 = a.y + c.y;
        const float v2 = a.z + c.z;
        const float v3 = a.w + c.w;
        const int k = q * 4;
        acc0 += v0 * W[2 * k + 0] + v1 * W[2 * k + 2] + v2 * W[2 * k + 4] + v3 * W[2 * k + 6];
        acc1 += v0 * W[2 * k + 1] + v1 * W[2 * k + 3] + v2 * W[2 * k + 5] + v3 * W[2 * k + 7];
    }
    float2 r;
    r.x = acc0;
    r.y = acc1;
    ((float2*)out)[node] = r;
}

// ===========================================================================
extern "C" void kernel_launch(void* const* d_in, const int* in_sizes, int n_in,
                              void* d_out, int out_size, void* d_ws, size_t ws_size,
                              hipStream_t stream) {
    const float* x   = (const float*)d_in[0];
    const int*   eix = (const int*)d_in[1];
    const float* W1  = (const float*)d_in[2];
    const float* b1  = (const float*)d_in[3];
    const float* W2  = (const float*)d_in[4];
    const float* b2  = (const float*)d_in[5];
    float*       out = (float*)d_out;

    const int n = in_sizes[0] / D;       // 50000
    const int E = in_sizes[1] / 2;       // 800000
    const int* src = eix;
    const int* dst = eix + E;

    const int lin_blocks = (n + 255) / 256;
    const size_t rowf = (size_t)n * D;           // floats per feature buffer

    // ws layout: aggr | h | cnt | off | cursor | btot(1024) | srcs
    const int nb = (n + 1023) / 1024;            // scan blocks
    const size_t need = (2 * rowf) * sizeof(float) +
                        (size_t)(3 * n + 1024 + E) * sizeof(int);

    float* aggr = (float*)d_ws;
    float* h    = aggr + rowf;

    if (ws_size < need) {
        // Fallback: atomic scatter path (round-1 baseline).
        const size_t aggr_bytes = rowf * sizeof(float);
        hipMemsetAsync(aggr, 0, aggr_bytes, stream);
        scatter_add_kernel<<<4096, 256, 0, stream>>>(x, src, dst, aggr, E);
        lin1_relu_kernel<<<lin_blocks, 256, 0, stream>>>(x, aggr, W1, b1, h, n);
        hipMemsetAsync(aggr, 0, aggr_bytes, stream);
        scatter_add_kernel<<<4096, 256, 0, stream>>>(h, src, dst, aggr, E);
        lin2_kernel<<<lin_blocks, 256, 0, stream>>>(h, aggr, W2, b2, out, n);
        return;
    }

    int* cnt    = (int*)(h + rowf);
    int* off    = cnt + n;
    int* cursor = off + n;
    int* btot   = cursor + n;
    int* srcs   = btot + 1024;

    // ---- CSR build (once; reused by both layers) ----
    hipMemsetAsync(cnt, 0, (size_t)n * sizeof(int), stream);
    hist_kernel<<<(E + 255) / 256, 256, 0, stream>>>(dst, cnt, E);
    blockscan_kernel<<<nb, 1024, 0, stream>>>(cnt, off, btot, n);
    scantot_kernel<<<1, 64, 0, stream>>>(btot, nb);
    addoff_kernel<<<(n + 255) / 256, 256, 0, stream>>>(off, cursor, btot, n);
    fill_kernel<<<(E + 255) / 256, 256, 0, stream>>>(src, dst, cursor, srcs, E);

    const int gth = n * D4;                       // 1.2M gather threads
    const int gather_blocks = (gth + 255) / 256;

    // ---- Layer 1 ----
    gather_kernel<<<gather_blocks, 256, 0, stream>>>(x, off, cnt, srcs, aggr, n);
    lin1_relu_kernel<<<lin_blocks, 256, 0, stream>>>(x, aggr, W1, b1, h, n);

    // ---- Layer 2 ----
    gather_kernel<<<gather_blocks, 256, 0, stream>>>(h, off, cnt, srcs, aggr, n);
    lin2_kernel<<<lin_blocks, 256, 0, stream>>>(h, aggr, W2, b2, out, n);
}

// Round 3
// 226.046 us; speedup vs baseline: 9.4194x; 1.4263x over previous
//
#include <hip/hip_runtime.h>

#define D 96
#define D4 24     // float4 groups per row
#define NT 64     // nodes per tile block
#define XPAD 97   // padded LDS row stride (97 mod 32 = 1 -> conflict-free)

// ===========================================================================
// CSR build: histogram of dst -> scan -> slot-fill of src ids.
// ===========================================================================
__global__ void hist_kernel(const int* __restrict__ dst, int* __restrict__ cnt, int E) {
    const int i = blockIdx.x * blockDim.x + threadIdx.x;
    if (i < E) atomicAdd(&cnt[dst[i]], 1);
}

__global__ void blockscan_kernel(const int* __restrict__ cnt, int* __restrict__ off,
                                 int* __restrict__ btot, int n) {
    __shared__ int tmp[1024];
    const int tid = threadIdx.x;
    const int gid = blockIdx.x * 1024 + tid;
    const int v = (gid < n) ? cnt[gid] : 0;
    tmp[tid] = v;
    __syncthreads();
    for (int ofs = 1; ofs < 1024; ofs <<= 1) {
        int t = 0;
        if (tid >= ofs) t = tmp[tid - ofs];
        __syncthreads();
        if (tid >= ofs) tmp[tid] += t;
        __syncthreads();
    }
    if (gid < n) off[gid] = tmp[tid] - v;
    if (tid == 1023) btot[blockIdx.x] = tmp[1023];
}

// Exclusive scan of block totals. Single wave handles nb<=64; serial fallback.
__global__ void scantot_kernel(int* __restrict__ btot, int nb) {
    const int tid = threadIdx.x;
    if (nb <= 64) {
        if (tid < 64) {
            const int v0 = (tid < nb) ? btot[tid] : 0;
            int v = v0;
            for (int ofs = 1; ofs < 64; ofs <<= 1) {
                const int t = __shfl_up(v, ofs, 64);
                if (tid >= ofs) v += t;
            }
            if (tid < nb) btot[tid] = v - v0;   // exclusive
        }
    } else if (tid == 0) {
        int run = 0;
        for (int i = 0; i < nb; ++i) { const int v = btot[i]; btot[i] = run; run += v; }
    }
}

__global__ void addoff_kernel(int* __restrict__ off, int* __restrict__ cursor,
                              const int* __restrict__ btot, int n) {
    const int i = blockIdx.x * blockDim.x + threadIdx.x;
    if (i < n) {
        const int o = off[i] + btot[i >> 10];
        off[i] = o;
        cursor[i] = o;
    }
}

__global__ void fill_kernel(const int* __restrict__ src, const int* __restrict__ dst,
                            int* __restrict__ cursor, int* __restrict__ srcs, int E) {
    const int i = blockIdx.x * blockDim.x + threadIdx.x;
    if (i < E) {
        const int p = atomicAdd(&cursor[dst[i]], 1);
        srcs[p] = src[i];
    }
}

// ===========================================================================
// Fused layer 1: per 64-node tile, gather (x[node] + sum x[src]) into LDS,
// then tile-GEMM vs W1 (in LDS) + bias + relu -> h.
// 4 threads per node; each owns 24 contiguous feats. All reg indices static.
// ===========================================================================
__global__ __launch_bounds__(256, 2)
void fused_lin1_kernel(const float* __restrict__ x,
                       const float* __restrict__ W,   // [96][96] row-major [k][o]
                       const float* __restrict__ b,   // [96]
                       const int* __restrict__ off,
                       const int* __restrict__ cnt,
                       const int* __restrict__ srcs,
                       float* __restrict__ h, int n) {
    __shared__ float Xs[NT][XPAD];     // 24.8 KB
    __shared__ float4 Ws[D * D4];      // 36.9 KB

    const int tid = threadIdx.x;
    for (int i = tid; i < D * D4; i += 256)
        Ws[i] = ((const float4*)W)[i];

    const int node_l = tid >> 2;       // 0..63
    const int qq = tid & 3;            // which 24-feat quarter
    const int node = blockIdx.x * NT + node_l;

    if (node < n) {
        // ---- Phase A: gather-accumulate into registers ----
        float acc[24];
        const float4* xr = ((const float4*)(x + (size_t)node * D)) + qq * 6;
#pragma unroll
        for (int j = 0; j < 6; ++j) {
            const float4 v = xr[j];
            acc[j * 4 + 0] = v.x; acc[j * 4 + 1] = v.y;
            acc[j * 4 + 2] = v.z; acc[j * 4 + 3] = v.w;
        }
        const int s0 = off[node];
        const int deg = cnt[node];
#pragma unroll 2
        for (int p = 0; p < deg; ++p) {
            const int s = srcs[s0 + p];
            const float4* fr = ((const float4*)(x + (size_t)s * D)) + qq * 6;
#pragma unroll
            for (int j = 0; j < 6; ++j) {
                const float4 v = fr[j];
                acc[j * 4 + 0] += v.x; acc[j * 4 + 1] += v.y;
                acc[j * 4 + 2] += v.z; acc[j * 4 + 3] += v.w;
            }
        }
#pragma unroll
        for (int j = 0; j < 24; ++j)
            Xs[node_l][qq * 24 + j] = acc[j];
    }
    __syncthreads();

    // ---- Phase B: GEMM. Thread computes outputs [qq*24, qq*24+24) ----
    if (node < n) {
        float4 oacc[6];
        const float4* bb = ((const float4*)b) + qq * 6;
#pragma unroll
        for (int j = 0; j < 6; ++j) oacc[j] = bb[j];

#pragma unroll 4
        for (int k = 0; k < D; ++k) {
            const float xv = Xs[node_l][k];
            const float4* wrow = Ws + k * D4 + qq * 6;
#pragma unroll
            for (int j = 0; j < 6; ++j) {
                const float4 w = wrow[j];
                oacc[j].x += xv * w.x; oacc[j].y += xv * w.y;
                oacc[j].z += xv * w.z; oacc[j].w += xv * w.w;
            }
        }
        float4* hr = ((float4*)(h + (size_t)node * D)) + qq * 6;
#pragma unroll
        for (int j = 0; j < 6; ++j) {
            float4 v = oacc[j];
            v.x = fmaxf(v.x, 0.0f); v.y = fmaxf(v.y, 0.0f);
            v.z = fmaxf(v.z, 0.0f); v.w = fmaxf(v.w, 0.0f);
            hr[j] = v;
        }
    }
}

// ===========================================================================
// Fused layer 2: gather (h[node] + sum h[src]) into LDS, then x W2 + b2.
// ===========================================================================
__global__ __launch_bounds__(256, 2)
void fused_lin2_kernel(const float* __restrict__ hbuf,
                       const float* __restrict__ W,   // [96][2]
                       const float* __restrict__ b,   // [2]
                       const int* __restrict__ off,
                       const int* __restrict__ cnt,
                       const int* __restrict__ srcs,
                       float* __restrict__ out, int n) {
    __shared__ float Xs[NT][XPAD];
    __shared__ float W2s[D * 2];

    const int tid = threadIdx.x;
    for (int i = tid; i < D * 2; i += 256) W2s[i] = W[i];

    const int node_l = tid >> 2;
    const int qq = tid & 3;
    const int node = blockIdx.x * NT + node_l;

    if (node < n) {
        float acc[24];
        const float4* xr = ((const float4*)(hbuf + (size_t)node * D)) + qq * 6;
#pragma unroll
        for (int j = 0; j < 6; ++j) {
            const float4 v = xr[j];
            acc[j * 4 + 0] = v.x; acc[j * 4 + 1] = v.y;
            acc[j * 4 + 2] = v.z; acc[j * 4 + 3] = v.w;
        }
        const int s0 = off[node];
        const int deg = cnt[node];
#pragma unroll 2
        for (int p = 0; p < deg; ++p) {
            const int s = srcs[s0 + p];
            const float4* fr = ((const float4*)(hbuf + (size_t)s * D)) + qq * 6;
#pragma unroll
            for (int j = 0; j < 6; ++j) {
                const float4 v = fr[j];
                acc[j * 4 + 0] += v.x; acc[j * 4 + 1] += v.y;
                acc[j * 4 + 2] += v.z; acc[j * 4 + 3] += v.w;
            }
        }
#pragma unroll
        for (int j = 0; j < 24; ++j)
            Xs[node_l][qq * 24 + j] = acc[j];
    }
    __syncthreads();

    // Phase B: thread t<128: node = t>>1, class c = t&1.
    if (tid < 128) {
        const int nl = tid >> 1;
        const int c = tid & 1;
        const int nd = blockIdx.x * NT + nl;
        if (nd < n) {
            float a = b[c];
#pragma unroll 4
            for (int k = 0; k < D; ++k)
                a += Xs[nl][k] * W2s[k * 2 + c];
            out[(size_t)nd * 2 + c] = a;
        }
    }
}

// ===========================================================================
// Fallback (atomic scatter) kernels — used only if ws too small.
// ===========================================================================
__global__ void scatter_add_kernel(const float* __restrict__ x,
                                   const int* __restrict__ src,
                                   const int* __restrict__ dst,
                                   float* __restrict__ aggr, int E) {
    const int total = E * D4;
    for (int i = blockIdx.x * blockDim.x + threadIdx.x; i < total;
         i += gridDim.x * blockDim.x) {
        const int e = i / D4;
        const int q = i - e * D4;
        const float4 v = ((const float4*)(x + (size_t)src[e] * D))[q];
        float* a = aggr + (size_t)dst[e] * D + q * 4;
        atomicAdd(a + 0, v.x);
        atomicAdd(a + 1, v.y);
        atomicAdd(a + 2, v.z);
        atomicAdd(a + 3, v.w);
    }
}

__global__ void lin1_relu_fb_kernel(const float* __restrict__ x,
                                    const float* __restrict__ aggr,
                                    const float* __restrict__ W,
                                    const float* __restrict__ b,
                                    float* __restrict__ h, int n) {
    const int t = blockIdx.x * blockDim.x + threadIdx.x;
    const int node = t >> 2, qq = t & 3;
    if (node >= n) return;
    float4 oacc[6];
#pragma unroll
    for (int j = 0; j < 6; ++j) oacc[j] = ((const float4*)b)[qq * 6 + j];
    for (int k = 0; k < D; ++k) {
        const float xv = x[(size_t)node * D + k] + aggr[(size_t)node * D + k];
#pragma unroll
        for (int j = 0; j < 6; ++j) {
            const float4 w = ((const float4*)W)[k * D4 + qq * 6 + j];
            oacc[j].x += xv * w.x; oacc[j].y += xv * w.y;
            oacc[j].z += xv * w.z; oacc[j].w += xv * w.w;
        }
    }
    float4* hr = ((float4*)(h + (size_t)node * D)) + qq * 6;
#pragma unroll
    for (int j = 0; j < 6; ++j) {
        float4 v = oacc[j];
        v.x = fmaxf(v.x, 0.0f); v.y = fmaxf(v.y, 0.0f);
        v.z = fmaxf(v.z, 0.0f); v.w = fmaxf(v.w, 0.0f);
        hr[j] = v;
    }
}

__global__ void lin2_fb_kernel(const float* __restrict__ h,
                               const float* __restrict__ aggr,
                               const float* __restrict__ W,
                               const float* __restrict__ b,
                               float* __restrict__ out, int n) {
    const int node = blockIdx.x * blockDim.x + threadIdx.x;
    if (node >= n) return;
    float a0 = b[0], a1 = b[1];
    for (int k = 0; k < D; ++k) {
        const float v = h[(size_t)node * D + k] + aggr[(size_t)node * D + k];
        a0 += v * W[2 * k + 0];
        a1 += v * W[2 * k + 1];
    }
    out[(size_t)node * 2 + 0] = a0;
    out[(size_t)node * 2 + 1] = a1;
}

// ===========================================================================
extern "C" void kernel_launch(void* const* d_in, const int* in_sizes, int n_in,
                              void* d_out, int out_size, void* d_ws, size_t ws_size,
                              hipStream_t stream) {
    const float* x   = (const float*)d_in[0];
    const int*   eix = (const int*)d_in[1];
    const float* W1  = (const float*)d_in[2];
    const float* b1  = (const float*)d_in[3];
    const float* W2  = (const float*)d_in[4];
    const float* b2  = (const float*)d_in[5];
    float*       out = (float*)d_out;

    const int n = in_sizes[0] / D;       // 50000
    const int E = in_sizes[1] / 2;       // 800000
    const int* src = eix;
    const int* dst = eix + E;

    const size_t rowf = (size_t)n * D;
    const int nb = (n + 1023) / 1024;

    // ws layout: h | cnt | off | cursor | btot(1024) | srcs
    const size_t need = rowf * sizeof(float) +
                        (size_t)(3 * n + 1024 + E) * sizeof(int);

    float* h = (float*)d_ws;

    if (ws_size < need) {
        // Fallback: atomic scatter path (needs 2*rowf floats).
        float* aggr = h + rowf;
        hipMemsetAsync(h, 0, rowf * sizeof(float), stream);
        scatter_add_kernel<<<4096, 256, 0, stream>>>(x, src, dst, h, E);
        lin1_relu_fb_kernel<<<(4 * n + 255) / 256, 256, 0, stream>>>(x, h, W1, b1, aggr, n);
        hipMemsetAsync(h, 0, rowf * sizeof(float), stream);
        scatter_add_kernel<<<4096, 256, 0, stream>>>(aggr, src, dst, h, E);
        lin2_fb_kernel<<<(n + 255) / 256, 256, 0, stream>>>(aggr, h, W2, b2, out, n);
        return;
    }

    int* cnt    = (int*)(h + rowf);
    int* off    = cnt + n;
    int* cursor = off + n;
    int* btot   = cursor + n;
    int* srcs   = btot + 1024;

    // ---- CSR build (once; reused by both layers) ----
    hipMemsetAsync(cnt, 0, (size_t)n * sizeof(int), stream);
    hist_kernel<<<(E + 255) / 256, 256, 0, stream>>>(dst, cnt, E);
    blockscan_kernel<<<nb, 1024, 0, stream>>>(cnt, off, btot, n);
    scantot_kernel<<<1, 64, 0, stream>>>(btot, nb);
    addoff_kernel<<<(n + 255) / 256, 256, 0, stream>>>(off, cursor, btot, n);
    fill_kernel<<<(E + 255) / 256, 256, 0, stream>>>(src, dst, cursor, srcs, E);

    const int tiles = (n + NT - 1) / NT;   // 782

    // ---- Layer 1 (fused gather + GEMM + relu) ----
    fused_lin1_kernel<<<tiles, 256, 0, stream>>>(x, W1, b1, off, cnt, srcs, h, n);

    // ---- Layer 2 (fused gather + small GEMM) ----
    fused_lin2_kernel<<<tiles, 256, 0, stream>>>(h, W2, b2, off, cnt, srcs, out, n);
}